// Round 5
// baseline (84.124 us; speedup 1.0000x reference)
//
#include <hip/hip_runtime.h>
#include <math.h>

#define B_   16
#define T_   2048
#define DIM_ 512
#define M_   (B_*T_)
#define AP   264   // As row stride in shorts (528 B): half-K tile, bank-floor access

typedef __attribute__((ext_vector_type(8))) short short8_t;   // 8 x bf16 bits
typedef __attribute__((ext_vector_type(4))) float f32x4;

__device__ __forceinline__ float clamp01(float x){ return fminf(fmaxf(x,0.f),1.f); }
__device__ __forceinline__ float clampf(float x,float lo,float hi){ return fminf(fmaxf(x,lo),hi); }
__device__ __forceinline__ float gelu_exact(float x){ return 0.5f*x*(1.f+erff(x*0.70710678118654752f)); }
__device__ __forceinline__ unsigned short bf16_rne(float f){
  unsigned u = __float_as_uint(f);
  unsigned r = (u + 0x7fffu + ((u>>16)&1u)) >> 16;
  return (unsigned short)r;
}
__device__ __forceinline__ float fast_tanh(float x){
  float e = __expf(2.0f*x);
  return 1.0f - 2.0f*__builtin_amdgcn_rcpf(e + 1.0f);
}
// tanh-form GELU (max abs dev from exact ~3e-4; used only in the wide epilogue)
__device__ __forceinline__ float gelu_fast(float x){
  float u = 0.7978845608028654f*fmaf(0.044715f*x, x*x, x);
  return 0.5f*x*(1.f + fast_tanh(u));
}
// packed f32x2 -> bf16x2 (RNE), 1 instruction
__device__ __forceinline__ unsigned cvt_pk_bf16(float lo, float hi){
  unsigned r;
  asm("v_cvt_pk_bf16_f32 %0, %1, %2" : "=v"(r) : "v"(lo), "v"(hi));
  return r;
}
__device__ __forceinline__ int idx32(int t){ return t + (t>>5); }  // pad stride 33

// ---------------------------------------------------------------------------
// P1: 160 blocks x 512 threads.
//  blk   0..127 : spk_ctx[b, s*64 .. s*64+64)  (b=blk>>3, s=blk&7)
//  blk 128..143 : EMA scan + excl cumsum       (b=blk-128)
//  blk 144..159 : rW1[0:512] -> bf16 Bt[kt][col][kk]  (kt=blk-144)
// ---------------------------------------------------------------------------
__global__ __launch_bounds__(512) void k_p1(
    const float* __restrict__ log_anchor, const float* __restrict__ unit_mask,
    const float* __restrict__ sealed_mask, const float* __restrict__ silence_mask,
    const float* __restrict__ local_rate_ema,
    const float* __restrict__ spk_embed, const float* __restrict__ spk_W,
    const float* __restrict__ spk_b, const float* __restrict__ rW1,
    float* __restrict__ lr_seq, float* __restrict__ prefix_prev,
    float* __restrict__ spk_ctx, unsigned short* __restrict__ BtG)
{
  __shared__ float shbuf[12672];
  const int tid = threadIdx.x;
  const int blk = blockIdx.x;

  if (blk < 128){
    const int b = blk >> 3, n0 = (blk & 7)*64;
    float* se      = shbuf;
    float* partial = shbuf + 512;
    se[tid] = spk_embed[b*512 + tid];
    __syncthreads();
    const int nq = tid & 15, q = tid >> 4;
    float a0=0.f, a1=0.f, a2=0.f, a3=0.f;
    const float* wp = spk_W + (q*16)*512 + n0 + nq*4;
    #pragma unroll
    for (int kk = 0; kk < 16; ++kk){
      float s = se[q*16 + kk];
      float4 v = *(const float4*)(wp + kk*512);
      a0 = fmaf(s, v.x, a0); a1 = fmaf(s, v.y, a1);
      a2 = fmaf(s, v.z, a2); a3 = fmaf(s, v.w, a3);
    }
    *(float4*)&partial[q*64 + nq*4] = make_float4(a0,a1,a2,a3);
    __syncthreads();
    if (tid < 64){
      float acc = spk_b[n0 + tid];
      #pragma unroll
      for (int qq = 0; qq < 32; ++qq) acc += partial[qq*64 + tid];
      spk_ctx[b*512 + n0 + tid] = tanhf(acc);
    }

  } else if (blk < 144){
    const int b = blk - 128;
    float* s_la = shbuf;
    float* s_um = shbuf + 2112;
    float* s_sm = shbuf + 4224;
    float* s_si = shbuf + 6336;
    float* s_or = shbuf + 8448;
    float* s_op = shbuf + 10560;
    #pragma unroll
    for (int p = 0; p < 4; ++p){
      int t = tid + p*512, g = b*T_ + t, ix = idx32(t);
      s_la[ix] = log_anchor[g];
      s_um[ix] = unit_mask[g];
      s_sm[ix] = sealed_mask[g];
      s_si[ix] = silence_mask[g];
    }
    __syncthreads();
    if (tid < 64){
      const float CE = (float)(1.0 - 0.95);
      const int base = tid*32;
      float A = 1.f, Bv = 0.f, S = 0.f;
      for (int j = 0; j < 32; ++j){
        int ix = idx32(base + j);
        float mask   = clamp01(s_um[ix]);
        float sealed = clamp01(s_sm[ix]);
        float sil    = clamp01(s_si[ix])*mask;
        float speech = mask*sealed*(1.f-sil);
        float cm = CE*speech;
        A  = (1.f-cm)*A;
        Bv = (1.f-cm)*Bv + cm*s_la[ix];
        S += speech;
      }
      float Ai=A, Bi=Bv, Si=S;
      for (int off = 1; off < 64; off <<= 1){
        float Ap=__shfl_up(Ai,off), Bp=__shfl_up(Bi,off), Sp=__shfl_up(Si,off);
        if (tid >= off){ Bi = Ai*Bp + Bi; Ai *= Ap; Si += Sp; }
      }
      float Ae=__shfl_up(Ai,1), Be=__shfl_up(Bi,1), Se=__shfl_up(Si,1);
      if (tid==0){ Ae=1.f; Be=0.f; Se=0.f; }
      float r  = Ae*local_rate_ema[b] + Be;
      float ps = Se;
      for (int j = 0; j < 32; ++j){
        int ix = idx32(base + j);
        float mask   = clamp01(s_um[ix]);
        float sealed = clamp01(s_sm[ix]);
        float sil    = clamp01(s_si[ix])*mask;
        float speech = mask*sealed*(1.f-sil);
        s_or[ix] = r;
        s_op[ix] = ps;
        r  += CE*speech*(s_la[ix]-r);
        ps += speech;
      }
    }
    __syncthreads();
    #pragma unroll
    for (int p = 0; p < 4; ++p){
      int t = tid + p*512, g = b*T_ + t, ix = idx32(t);
      lr_seq[g]      = s_or[ix];
      prefix_prev[g] = s_op[ix];
    }

  } else {
    const int kt = blk - 144;
    unsigned short* sb = (unsigned short*)shbuf;   // [32][512]
    #pragma unroll
    for (int p = 0; p < 32; ++p){
      int id = tid + p*512;
      int kl = id >> 9, col = id & 511;
      sb[kl*512 + col] = bf16_rne(rW1[(kt*32 + kl)*512 + col]);
    }
    __syncthreads();
    const int col = tid;
    unsigned q[16];
    #pragma unroll
    for (int p = 0; p < 16; ++p)
      q[p] = (unsigned)sb[(2*p)*512 + col] | ((unsigned)sb[(2*p+1)*512 + col] << 16);
    uint4* dst = (uint4*)(BtG + kt*16384 + col*32);
    dst[0] = make_uint4(q[0], q[1], q[2], q[3]);
    dst[1] = make_uint4(q[4], q[5], q[6], q[7]);
    dst[2] = make_uint4(q[8], q[9], q[10], q[11]);
    dst[3] = make_uint4(q[12], q[13], q[14], q[15]);
  }
}

// ---------------------------------------------------------------------------
// P2: 256 blocks x 512 threads.
//  blk   0..127 : spk_pb[b, slice] = sc@rW1[512:1024,slice] + rb1
//  blk 128..255 : cpart[b][s] = sum_slice gelu(ac)*cW2   (coarse partials)
// ---------------------------------------------------------------------------
__global__ __launch_bounds__(512) void k_p2(
    const float* __restrict__ spk_ctx, const float* __restrict__ global_rate,
    const float* __restrict__ cW1, const float* __restrict__ cb1,
    const float* __restrict__ cW2, const float* __restrict__ rW1,
    const float* __restrict__ rb1,
    float* __restrict__ spk_pb, float* __restrict__ cpart)
{
  __shared__ float sc[512];
  __shared__ float partial[32*64];
  const int tid = threadIdx.x;
  const int blk = blockIdx.x;
  const bool isAC = blk >= 128;
  const int bb = isAC ? (blk - 128) : blk;
  const int b = bb >> 3, s = bb & 7, n0 = s*64;

  sc[tid] = spk_ctx[b*512 + tid];
  __syncthreads();
  const int nq = tid & 15, q = tid >> 4;
  const float* mat = isAC ? cW1 : (rW1 + 512*512);
  float a0=0.f, a1=0.f, a2=0.f, a3=0.f;
  const float* wp = mat + (q*16)*512 + n0 + nq*4;
  #pragma unroll
  for (int kk = 0; kk < 16; ++kk){
    float sv = sc[q*16 + kk];
    float4 v = *(const float4*)(wp + kk*512);
    a0 = fmaf(sv, v.x, a0); a1 = fmaf(sv, v.y, a1);
    a2 = fmaf(sv, v.z, a2); a3 = fmaf(sv, v.w, a3);
  }
  *(float4*)&partial[q*64 + nq*4] = make_float4(a0,a1,a2,a3);
  __syncthreads();
  if (tid < 64){
    const int n = n0 + tid;
    float acc = 0.f;
    #pragma unroll
    for (int qq = 0; qq < 32; ++qq) acc += partial[qq*64 + tid];
    if (!isAC){
      spk_pb[b*512 + n] = acc + rb1[n];
    } else {
      float ac = acc + cb1[n] + global_rate[b]*cW1[512*512 + n];
      float g  = gelu_exact(ac)*cW2[n];
      g += __shfl_xor(g,1);  g += __shfl_xor(g,2);  g += __shfl_xor(g,4);
      g += __shfl_xor(g,8);  g += __shfl_xor(g,16); g += __shfl_xor(g,32);
      if (tid == 0) cpart[b*8 + s] = g;
    }
  }
}

// ---------------------------------------------------------------------------
// K3: MFMA heavy kernel. Block = 8 waves (512 thr), 64 rows x all 512 cols.
// Wave w owns cols [w*64, w*64+64) -> acc[4][4] = 64 VGPR (4 waves/SIMD target).
// A computed in 2 half-K tiles (64x256 bf16, AP=264 -> ~39 KB LDS, 2 blocks/CU).
// Grid = 512 blocks = exactly one resident generation.
// ---------------------------------------------------------------------------
__global__ __launch_bounds__(512, 4) void k_heavy(
    const int*   __restrict__ content_units, const float* __restrict__ log_anchor,
    const float* __restrict__ unit_mask,     const float* __restrict__ sealed_mask,
    const float* __restrict__ sep_hint,      const float* __restrict__ edge_cue,
    const float* __restrict__ global_rate,   const float* __restrict__ silence_mask,
    const float* __restrict__ embed,         const float* __restrict__ feat_W,
    const float* __restrict__ feat_b,        const float* __restrict__ rW1,
    const float* __restrict__ rW2,           const float* __restrict__ rb2,
    const float* __restrict__ cb2,
    const float* __restrict__ lr_seq,        const float* __restrict__ prefix_prev,
    const float* __restrict__ spk_pb,        const float* __restrict__ cpart,
    const unsigned short* __restrict__ BtG,
    float* __restrict__ out)
{
  __shared__ unsigned short As_s[64*AP];    // 33792 B
  __shared__ float r_la[64], r_lr[64], r_sil[64], r_sep[64], r_edge[64], r_mask[64];
  __shared__ int   r_u[64];
  __shared__ float r_gt[64], r_speech[64], r_silc[64], r_resmul[64], r_tau[64];
  __shared__ float pdred[8][64];

  const int m0   = blockIdx.x*64;
  const int b    = m0 >> 11;
  const int tid  = threadIdx.x;
  const int lane = tid & 63;
  const int w    = tid >> 6;                // 0..7
  const int l15  = lane & 15, kg = lane >> 4;

  if (tid < 64){
    int m = m0 + tid;
    float csum = cb2[0];
    #pragma unroll
    for (int s = 0; s < 8; ++s) csum += cpart[b*8 + s];
    float coarse = 0.2f*tanhf(csum);
    float mask   = clamp01(unit_mask[m]);
    float sealed = clamp01(sealed_mask[m]);
    float sil    = clamp01(silence_mask[m])*mask;
    float commit = mask*sealed;
    float silc   = commit*sil;
    float speech = commit*(1.f-sil);
    float la = log_anchor[m];
    float lr = lr_seq[m];
    float gap = clampf(global_rate[b]-lr, -0.35f, 0.35f)*commit;
    float gt  = (gap + coarse*commit)*commit;
    float cold = clamp01(prefix_prev[m]*0.5f);
    float dur  = expf(la);
    float shortv = clamp01(fmaxf(dur,1.f)-1.f);
    r_la[tid]=la; r_lr[tid]=lr; r_sil[tid]=sil;
    r_sep[tid]=sep_hint[m]; r_edge[tid]=edge_cue[m]; r_mask[tid]=mask;
    r_u[tid]=content_units[m];
    r_gt[tid]=gt; r_speech[tid]=speech; r_silc[tid]=silc;
    r_resmul[tid]=cold*shortv*speech;
    r_tau[tid]=0.35f*((dur<2.0f)?0.35f:1.0f);
  }
  __syncthreads();

  f32x4 acc[4][4];
  #pragma unroll
  for (int r=0;r<4;++r)
    #pragma unroll
    for (int c=0;c<4;++c) acc[r][c] = (f32x4)0.0f;

  // A-compute assignment: thread = 4 rows x 1 chunk (8 els); feat amortized 4x
  const int rg  = (tid >> 5)*4;             // row group: 0,4,...,60
  const int acv = tid & 31;                 // chunk 0..31 within half
  const unsigned short* bwave = BtG + (w*64 + l15)*32 + kg*8;

  for (int h = 0; h < 2; ++h){
    __syncthreads();   // As free (prev half's fragment reads done)
    {
      const int jg = h*256 + acv*8;
      union { float4 v[2]; float f[8]; } w0U, w1U, w2U, w3U, w4U, bU;
      w0U.v[0] = *(const float4*)(feat_W + jg);        w0U.v[1] = *(const float4*)(feat_W + jg + 4);
      w1U.v[0] = *(const float4*)(feat_W + 512 + jg);  w1U.v[1] = *(const float4*)(feat_W + 512 + jg + 4);
      w2U.v[0] = *(const float4*)(feat_W + 1024 + jg); w2U.v[1] = *(const float4*)(feat_W + 1024 + jg + 4);
      w3U.v[0] = *(const float4*)(feat_W + 1536 + jg); w3U.v[1] = *(const float4*)(feat_W + 1536 + jg + 4);
      w4U.v[0] = *(const float4*)(feat_W + 2048 + jg); w4U.v[1] = *(const float4*)(feat_W + 2048 + jg + 4);
      bU.v[0]  = *(const float4*)(feat_b + jg);        bU.v[1]  = *(const float4*)(feat_b + jg + 4);
      #pragma unroll
      for (int i = 0; i < 4; ++i){
        const int row = rg + i;
        const int u   = r_u[row];
        const float la=r_la[row], lr=r_lr[row], si=r_sil[row],
                    sp=r_sep[row], ed=r_edge[row], mk=r_mask[row];
        union { float4 v[2]; float f[8]; } eU;
        const float* eb = embed + (size_t)u*DIM_ + jg;
        eU.v[0] = *(const float4*)eb;
        eU.v[1] = *(const float4*)(eb + 4);
        unsigned pk[4];
        #pragma unroll
        for (int p = 0; p < 4; ++p){
          float fA = eU.f[2*p]   + bU.f[2*p]   + la*w0U.f[2*p]   + lr*w1U.f[2*p]
                   + si*w2U.f[2*p]   + sp*w3U.f[2*p]   + ed*w4U.f[2*p];
          float fB = eU.f[2*p+1] + bU.f[2*p+1] + la*w0U.f[2*p+1] + lr*w1U.f[2*p+1]
                   + si*w2U.f[2*p+1] + sp*w3U.f[2*p+1] + ed*w4U.f[2*p+1];
          pk[p] = cvt_pk_bf16(fast_tanh(fA)*mk, fast_tanh(fB)*mk);
        }
        *(uint4*)&As_s[row*AP + acv*8] = make_uint4(pk[0], pk[1], pk[2], pk[3]);
      }
    }
    __syncthreads();   // As ready

    #pragma unroll 2
    for (int kt = 0; kt < 8; ++kt){
      const unsigned short* bkt = bwave + (h*8 + kt)*16384;
      short8_t af[4], bfr[4];
      #pragma unroll
      for (int r=0;r<4;++r)
        af[r] = *(const short8_t*)&As_s[(r*16 + l15)*AP + kt*32 + kg*8];
      #pragma unroll
      for (int c=0;c<4;++c)
        bfr[c] = *(const short8_t*)(bkt + c*512);
      #pragma unroll
      for (int r=0;r<4;++r)
        #pragma unroll
        for (int c=0;c<4;++c)
          acc[r][c] = __builtin_amdgcn_mfma_f32_16x16x32_bf16(af[r], bfr[c], acc[r][c], 0, 0, 0);
    }
  }

  // --- epilogue: x = acc + spk_pb[col] + gt[row]*wb[col]; gelu; dot rW2 ---
  const int colb = w*64 + l15;
  float stv[4], wbv[4], w2v[4];
  #pragma unroll
  for (int c=0;c<4;++c){
    int col = colb + c*16;
    stv[c] = spk_pb[b*DIM_ + col];
    wbv[c] = rW1[1024*DIM_ + col];
    w2v[c] = rW2[col];
  }
  #pragma unroll
  for (int r=0;r<4;++r){
    #pragma unroll
    for (int g=0; g<4; ++g){
      int row = r*16 + kg*4 + g;           // C/D: row=(lane>>4)*4+reg
      float gt = r_gt[row];
      float s = 0.f;
      #pragma unroll
      for (int c=0;c<4;++c){
        float x = acc[r][c][g] + stv[c] + gt*wbv[c];
        s += gelu_fast(x)*w2v[c];
      }
      s += __shfl_xor(s,1); s += __shfl_xor(s,2);
      s += __shfl_xor(s,4); s += __shfl_xor(s,8);
      if (l15 == 0) pdred[w][row] = s;
    }
  }
  __syncthreads();
  if (tid < 64){
    float v = rb2[0];
    #pragma unroll
    for (int ww = 0; ww < 8; ++ww) v += pdred[ww][tid];
    float residual = 0.35f*tanhf(v) * r_resmul[tid];
    float gt = r_gt[tid];
    out[m0+tid] = clampf(gt + residual, -1.2f, 1.2f)*r_speech[tid]
                + clampf(gt, -r_tau[tid], r_tau[tid])*r_silc[tid];
  }
}

// ---------------------------------------------------------------------------
extern "C" void kernel_launch(void* const* d_in, const int* in_sizes, int n_in,
                              void* d_out, int out_size, void* d_ws, size_t ws_size,
                              hipStream_t stream)
{
  const int*   content_units  = (const int*)  d_in[0];
  const float* log_anchor     = (const float*)d_in[1];
  const float* unit_mask      = (const float*)d_in[2];
  const float* sealed_mask    = (const float*)d_in[3];
  const float* sep_hint       = (const float*)d_in[4];
  const float* edge_cue       = (const float*)d_in[5];
  const float* global_rate    = (const float*)d_in[6];
  const float* local_rate_ema = (const float*)d_in[7];
  const float* silence_mask   = (const float*)d_in[8];
  const float* spk_embed      = (const float*)d_in[9];
  const float* embed          = (const float*)d_in[10];
  const float* feat_W         = (const float*)d_in[11];
  const float* feat_b         = (const float*)d_in[12];
  const float* spk_W          = (const float*)d_in[13];
  const float* spk_b          = (const float*)d_in[14];
  const float* cW1            = (const float*)d_in[15];
  const float* cb1            = (const float*)d_in[16];
  const float* cW2            = (const float*)d_in[17];
  const float* cb2            = (const float*)d_in[18];
  const float* rW1            = (const float*)d_in[19];
  const float* rb1            = (const float*)d_in[20];
  const float* rW2            = (const float*)d_in[21];
  const float* rb2            = (const float*)d_in[22];
  float* out = (float*)d_out;

  float* ws       = (float*)d_ws;
  float* lr_seq   = ws;                  // 32768
  float* prefix   = ws + 32768;          // 32768
  float* spk_ctx  = ws + 65536;          // 8192
  float* spk_pb   = ws + 73728;          // 8192
  float* cpart    = ws + 81920;          // 128
  unsigned short* BtG = (unsigned short*)(ws + 82048);   // 512 KB bf16

  k_p1<<<160, 512, 0, stream>>>(log_anchor, unit_mask, sealed_mask, silence_mask,
                                local_rate_ema, spk_embed, spk_W, spk_b, rW1,
                                lr_seq, prefix, spk_ctx, BtG);
  k_p2<<<256, 512, 0, stream>>>(spk_ctx, global_rate, cW1, cb1, cW2, rW1, rb1,
                                spk_pb, cpart);
  k_heavy<<<M_/64, 512, 0, stream>>>(content_units, log_anchor, unit_mask, sealed_mask,
                                     sep_hint, edge_cue, global_rate, silence_mask,
                                     embed, feat_W, feat_b, rW1, rW2, rb2, cb2,
                                     lr_seq, prefix, spk_pb, cpart, BtG, out);
}

// Round 6
// 53.719 us; speedup vs baseline: 1.5660x; 1.5660x over previous
//
#include <hip/hip_runtime.h>
#include <math.h>

#define B_   16
#define T_   2048
#define DIM_ 512
#define M_   (B_*T_)
#define AP   264   // As row stride in shorts (528 B): half-K tile, bank-floor access

typedef __attribute__((ext_vector_type(8))) short short8_t;   // 8 x bf16 bits
typedef __attribute__((ext_vector_type(4))) float f32x4;

__device__ __forceinline__ float clamp01(float x){ return fminf(fmaxf(x,0.f),1.f); }
__device__ __forceinline__ float clampf(float x,float lo,float hi){ return fminf(fmaxf(x,lo),hi); }
__device__ __forceinline__ float gelu_exact(float x){ return 0.5f*x*(1.f+erff(x*0.70710678118654752f)); }
__device__ __forceinline__ unsigned short bf16_rne(float f){
  unsigned u = __float_as_uint(f);
  unsigned r = (u + 0x7fffu + ((u>>16)&1u)) >> 16;
  return (unsigned short)r;
}
__device__ __forceinline__ float fast_tanh(float x){
  float e = __expf(2.0f*x);
  return 1.0f - 2.0f*__builtin_amdgcn_rcpf(e + 1.0f);
}
// tanh-form GELU (max abs dev from exact ~3e-4; used only in the wide epilogue)
__device__ __forceinline__ float gelu_fast(float x){
  float u = 0.7978845608028654f*fmaf(0.044715f*x, x*x, x);
  return 0.5f*x*(1.f + fast_tanh(u));
}
// packed f32x2 -> bf16x2 (RNE), 1 instruction
__device__ __forceinline__ unsigned cvt_pk_bf16(float lo, float hi){
  unsigned r;
  asm("v_cvt_pk_bf16_f32 %0, %1, %2" : "=v"(r) : "v"(lo), "v"(hi));
  return r;
}
__device__ __forceinline__ int idx32(int t){ return t + (t>>5); }  // pad stride 33

// ---------------------------------------------------------------------------
// P1: 160 blocks x 512 threads.
//  blk   0..127 : spk_ctx[b, s*64 .. s*64+64)  (b=blk>>3, s=blk&7)
//  blk 128..143 : EMA scan + excl cumsum       (b=blk-128)
//  blk 144..159 : rW1[0:512] -> bf16 Bt[kt][col][kk]  (kt=blk-144)
// ---------------------------------------------------------------------------
__global__ __launch_bounds__(512) void k_p1(
    const float* __restrict__ log_anchor, const float* __restrict__ unit_mask,
    const float* __restrict__ sealed_mask, const float* __restrict__ silence_mask,
    const float* __restrict__ local_rate_ema,
    const float* __restrict__ spk_embed, const float* __restrict__ spk_W,
    const float* __restrict__ spk_b, const float* __restrict__ rW1,
    float* __restrict__ lr_seq, float* __restrict__ prefix_prev,
    float* __restrict__ spk_ctx, unsigned short* __restrict__ BtG)
{
  __shared__ float shbuf[12672];
  const int tid = threadIdx.x;
  const int blk = blockIdx.x;

  if (blk < 128){
    const int b = blk >> 3, n0 = (blk & 7)*64;
    float* se      = shbuf;
    float* partial = shbuf + 512;
    se[tid] = spk_embed[b*512 + tid];
    __syncthreads();
    const int nq = tid & 15, q = tid >> 4;
    float a0=0.f, a1=0.f, a2=0.f, a3=0.f;
    const float* wp = spk_W + (q*16)*512 + n0 + nq*4;
    #pragma unroll
    for (int kk = 0; kk < 16; ++kk){
      float s = se[q*16 + kk];
      float4 v = *(const float4*)(wp + kk*512);
      a0 = fmaf(s, v.x, a0); a1 = fmaf(s, v.y, a1);
      a2 = fmaf(s, v.z, a2); a3 = fmaf(s, v.w, a3);
    }
    *(float4*)&partial[q*64 + nq*4] = make_float4(a0,a1,a2,a3);
    __syncthreads();
    if (tid < 64){
      float acc = spk_b[n0 + tid];
      #pragma unroll
      for (int qq = 0; qq < 32; ++qq) acc += partial[qq*64 + tid];
      spk_ctx[b*512 + n0 + tid] = tanhf(acc);
    }

  } else if (blk < 144){
    const int b = blk - 128;
    float* s_la = shbuf;
    float* s_um = shbuf + 2112;
    float* s_sm = shbuf + 4224;
    float* s_si = shbuf + 6336;
    float* s_or = shbuf + 8448;
    float* s_op = shbuf + 10560;
    #pragma unroll
    for (int p = 0; p < 4; ++p){
      int t = tid + p*512, g = b*T_ + t, ix = idx32(t);
      s_la[ix] = log_anchor[g];
      s_um[ix] = unit_mask[g];
      s_sm[ix] = sealed_mask[g];
      s_si[ix] = silence_mask[g];
    }
    __syncthreads();
    if (tid < 64){
      const float CE = (float)(1.0 - 0.95);
      const int base = tid*32;
      float A = 1.f, Bv = 0.f, S = 0.f;
      for (int j = 0; j < 32; ++j){
        int ix = idx32(base + j);
        float mask   = clamp01(s_um[ix]);
        float sealed = clamp01(s_sm[ix]);
        float sil    = clamp01(s_si[ix])*mask;
        float speech = mask*sealed*(1.f-sil);
        float cm = CE*speech;
        A  = (1.f-cm)*A;
        Bv = (1.f-cm)*Bv + cm*s_la[ix];
        S += speech;
      }
      float Ai=A, Bi=Bv, Si=S;
      for (int off = 1; off < 64; off <<= 1){
        float Ap=__shfl_up(Ai,off), Bp=__shfl_up(Bi,off), Sp=__shfl_up(Si,off);
        if (tid >= off){ Bi = Ai*Bp + Bi; Ai *= Ap; Si += Sp; }
      }
      float Ae=__shfl_up(Ai,1), Be=__shfl_up(Bi,1), Se=__shfl_up(Si,1);
      if (tid==0){ Ae=1.f; Be=0.f; Se=0.f; }
      float r  = Ae*local_rate_ema[b] + Be;
      float ps = Se;
      for (int j = 0; j < 32; ++j){
        int ix = idx32(base + j);
        float mask   = clamp01(s_um[ix]);
        float sealed = clamp01(s_sm[ix]);
        float sil    = clamp01(s_si[ix])*mask;
        float speech = mask*sealed*(1.f-sil);
        s_or[ix] = r;
        s_op[ix] = ps;
        r  += CE*speech*(s_la[ix]-r);
        ps += speech;
      }
    }
    __syncthreads();
    #pragma unroll
    for (int p = 0; p < 4; ++p){
      int t = tid + p*512, g = b*T_ + t, ix = idx32(t);
      lr_seq[g]      = s_or[ix];
      prefix_prev[g] = s_op[ix];
    }

  } else {
    const int kt = blk - 144;
    unsigned short* sb = (unsigned short*)shbuf;   // [32][512]
    #pragma unroll
    for (int p = 0; p < 32; ++p){
      int id = tid + p*512;
      int kl = id >> 9, col = id & 511;
      sb[kl*512 + col] = bf16_rne(rW1[(kt*32 + kl)*512 + col]);
    }
    __syncthreads();
    const int col = tid;
    unsigned q[16];
    #pragma unroll
    for (int p = 0; p < 16; ++p)
      q[p] = (unsigned)sb[(2*p)*512 + col] | ((unsigned)sb[(2*p+1)*512 + col] << 16);
    uint4* dst = (uint4*)(BtG + kt*16384 + col*32);
    dst[0] = make_uint4(q[0], q[1], q[2], q[3]);
    dst[1] = make_uint4(q[4], q[5], q[6], q[7]);
    dst[2] = make_uint4(q[8], q[9], q[10], q[11]);
    dst[3] = make_uint4(q[12], q[13], q[14], q[15]);
  }
}

// ---------------------------------------------------------------------------
// P2: 256 blocks x 512 threads.
//  blk   0..127 : spk_pb[b, slice] = sc@rW1[512:1024,slice] + rb1
//  blk 128..255 : cpart[b][s] = sum_slice gelu(ac)*cW2   (coarse partials)
// ---------------------------------------------------------------------------
__global__ __launch_bounds__(512) void k_p2(
    const float* __restrict__ spk_ctx, const float* __restrict__ global_rate,
    const float* __restrict__ cW1, const float* __restrict__ cb1,
    const float* __restrict__ cW2, const float* __restrict__ rW1,
    const float* __restrict__ rb1,
    float* __restrict__ spk_pb, float* __restrict__ cpart)
{
  __shared__ float sc[512];
  __shared__ float partial[32*64];
  const int tid = threadIdx.x;
  const int blk = blockIdx.x;
  const bool isAC = blk >= 128;
  const int bb = isAC ? (blk - 128) : blk;
  const int b = bb >> 3, s = bb & 7, n0 = s*64;

  sc[tid] = spk_ctx[b*512 + tid];
  __syncthreads();
  const int nq = tid & 15, q = tid >> 4;
  const float* mat = isAC ? cW1 : (rW1 + 512*512);
  float a0=0.f, a1=0.f, a2=0.f, a3=0.f;
  const float* wp = mat + (q*16)*512 + n0 + nq*4;
  #pragma unroll
  for (int kk = 0; kk < 16; ++kk){
    float sv = sc[q*16 + kk];
    float4 v = *(const float4*)(wp + kk*512);
    a0 = fmaf(sv, v.x, a0); a1 = fmaf(sv, v.y, a1);
    a2 = fmaf(sv, v.z, a2); a3 = fmaf(sv, v.w, a3);
  }
  *(float4*)&partial[q*64 + nq*4] = make_float4(a0,a1,a2,a3);
  __syncthreads();
  if (tid < 64){
    const int n = n0 + tid;
    float acc = 0.f;
    #pragma unroll
    for (int qq = 0; qq < 32; ++qq) acc += partial[qq*64 + tid];
    if (!isAC){
      spk_pb[b*512 + n] = acc + rb1[n];
    } else {
      float ac = acc + cb1[n] + global_rate[b]*cW1[512*512 + n];
      float g  = gelu_exact(ac)*cW2[n];
      g += __shfl_xor(g,1);  g += __shfl_xor(g,2);  g += __shfl_xor(g,4);
      g += __shfl_xor(g,8);  g += __shfl_xor(g,16); g += __shfl_xor(g,32);
      if (tid == 0) cpart[b*8 + s] = g;
    }
  }
}

// ---------------------------------------------------------------------------
// K3: MFMA heavy kernel. Block = 8 waves (512 thr), 64 rows x all 512 cols.
// Wave w owns cols [w*64, w*64+64) -> acc[4][4] = 64 AGPR.
// __launch_bounds__(512,3): ~170-reg cap -> no spills (r5's (512,4)=128 spilled),
// 3 waves/SIMD occupancy target.
// A computed in 2 half-K tiles (64x256 bf16, AP=264 -> ~38 KB LDS).
// ---------------------------------------------------------------------------
__global__ __launch_bounds__(512, 3) void k_heavy(
    const int*   __restrict__ content_units, const float* __restrict__ log_anchor,
    const float* __restrict__ unit_mask,     const float* __restrict__ sealed_mask,
    const float* __restrict__ sep_hint,      const float* __restrict__ edge_cue,
    const float* __restrict__ global_rate,   const float* __restrict__ silence_mask,
    const float* __restrict__ embed,         const float* __restrict__ feat_W,
    const float* __restrict__ feat_b,        const float* __restrict__ rW1,
    const float* __restrict__ rW2,           const float* __restrict__ rb2,
    const float* __restrict__ cb2,
    const float* __restrict__ lr_seq,        const float* __restrict__ prefix_prev,
    const float* __restrict__ spk_pb,        const float* __restrict__ cpart,
    const unsigned short* __restrict__ BtG,
    float* __restrict__ out)
{
  __shared__ unsigned short As_s[64*AP];    // 33792 B
  __shared__ float r_la[64], r_lr[64], r_sil[64], r_sep[64], r_edge[64], r_mask[64];
  __shared__ int   r_u[64];
  __shared__ float r_gt[64], r_speech[64], r_silc[64], r_resmul[64], r_tau[64];
  __shared__ float pdred[8][64];

  const int m0   = blockIdx.x*64;
  const int b    = m0 >> 11;
  const int tid  = threadIdx.x;
  const int lane = tid & 63;
  const int w    = tid >> 6;                // 0..7
  const int l15  = lane & 15, kg = lane >> 4;

  if (tid < 64){
    int m = m0 + tid;
    float csum = cb2[0];
    #pragma unroll
    for (int s = 0; s < 8; ++s) csum += cpart[b*8 + s];
    float coarse = 0.2f*tanhf(csum);
    float mask   = clamp01(unit_mask[m]);
    float sealed = clamp01(sealed_mask[m]);
    float sil    = clamp01(silence_mask[m])*mask;
    float commit = mask*sealed;
    float silc   = commit*sil;
    float speech = commit*(1.f-sil);
    float la = log_anchor[m];
    float lr = lr_seq[m];
    float gap = clampf(global_rate[b]-lr, -0.35f, 0.35f)*commit;
    float gt  = (gap + coarse*commit)*commit;
    float cold = clamp01(prefix_prev[m]*0.5f);
    float dur  = expf(la);
    float shortv = clamp01(fmaxf(dur,1.f)-1.f);
    r_la[tid]=la; r_lr[tid]=lr; r_sil[tid]=sil;
    r_sep[tid]=sep_hint[m]; r_edge[tid]=edge_cue[m]; r_mask[tid]=mask;
    r_u[tid]=content_units[m];
    r_gt[tid]=gt; r_speech[tid]=speech; r_silc[tid]=silc;
    r_resmul[tid]=cold*shortv*speech;
    r_tau[tid]=0.35f*((dur<2.0f)?0.35f:1.0f);
  }
  __syncthreads();

  f32x4 acc[4][4];
  #pragma unroll
  for (int r=0;r<4;++r)
    #pragma unroll
    for (int c=0;c<4;++c) acc[r][c] = (f32x4)0.0f;

  // A-compute assignment: thread = 4 rows x 1 chunk (8 els); feat amortized 4x
  const int rg  = (tid >> 5)*4;             // row group: 0,4,...,60
  const int acv = tid & 31;                 // chunk 0..31 within half
  const unsigned short* bwave = BtG + (w*64 + l15)*32 + kg*8;

  for (int h = 0; h < 2; ++h){
    __syncthreads();   // As free (prev half's fragment reads done)
    {
      const int jg = h*256 + acv*8;
      union { float4 v[2]; float f[8]; } w0U, w1U, w2U, w3U, w4U, bU;
      w0U.v[0] = *(const float4*)(feat_W + jg);        w0U.v[1] = *(const float4*)(feat_W + jg + 4);
      w1U.v[0] = *(const float4*)(feat_W + 512 + jg);  w1U.v[1] = *(const float4*)(feat_W + 512 + jg + 4);
      w2U.v[0] = *(const float4*)(feat_W + 1024 + jg); w2U.v[1] = *(const float4*)(feat_W + 1024 + jg + 4);
      w3U.v[0] = *(const float4*)(feat_W + 1536 + jg); w3U.v[1] = *(const float4*)(feat_W + 1536 + jg + 4);
      w4U.v[0] = *(const float4*)(feat_W + 2048 + jg); w4U.v[1] = *(const float4*)(feat_W + 2048 + jg + 4);
      bU.v[0]  = *(const float4*)(feat_b + jg);        bU.v[1]  = *(const float4*)(feat_b + jg + 4);
      #pragma unroll
      for (int i = 0; i < 4; ++i){
        const int row = rg + i;
        const int u   = r_u[row];
        const float la=r_la[row], lr=r_lr[row], si=r_sil[row],
                    sp=r_sep[row], ed=r_edge[row], mk=r_mask[row];
        union { float4 v[2]; float f[8]; } eU;
        const float* eb = embed + (size_t)u*DIM_ + jg;
        eU.v[0] = *(const float4*)eb;
        eU.v[1] = *(const float4*)(eb + 4);
        unsigned pk[4];
        #pragma unroll
        for (int p = 0; p < 4; ++p){
          float fA = eU.f[2*p]   + bU.f[2*p]   + la*w0U.f[2*p]   + lr*w1U.f[2*p]
                   + si*w2U.f[2*p]   + sp*w3U.f[2*p]   + ed*w4U.f[2*p];
          float fB = eU.f[2*p+1] + bU.f[2*p+1] + la*w0U.f[2*p+1] + lr*w1U.f[2*p+1]
                   + si*w2U.f[2*p+1] + sp*w3U.f[2*p+1] + ed*w4U.f[2*p+1];
          pk[p] = cvt_pk_bf16(fast_tanh(fA)*mk, fast_tanh(fB)*mk);
        }
        *(uint4*)&As_s[row*AP + acv*8] = make_uint4(pk[0], pk[1], pk[2], pk[3]);
      }
    }
    __syncthreads();   // As ready

    #pragma unroll 4
    for (int kt = 0; kt < 8; ++kt){
      const unsigned short* bkt = bwave + (h*8 + kt)*16384;
      short8_t af[4], bfr[4];
      #pragma unroll
      for (int r=0;r<4;++r)
        af[r] = *(const short8_t*)&As_s[(r*16 + l15)*AP + kt*32 + kg*8];
      #pragma unroll
      for (int c=0;c<4;++c)
        bfr[c] = *(const short8_t*)(bkt + c*512);
      #pragma unroll
      for (int r=0;r<4;++r)
        #pragma unroll
        for (int c=0;c<4;++c)
          acc[r][c] = __builtin_amdgcn_mfma_f32_16x16x32_bf16(af[r], bfr[c], acc[r][c], 0, 0, 0);
    }
  }

  // --- epilogue: x = acc + spk_pb[col] + gt[row]*wb[col]; gelu; dot rW2 ---
  const int colb = w*64 + l15;
  float stv[4], wbv[4], w2v[4];
  #pragma unroll
  for (int c=0;c<4;++c){
    int col = colb + c*16;
    stv[c] = spk_pb[b*DIM_ + col];
    wbv[c] = rW1[1024*DIM_ + col];
    w2v[c] = rW2[col];
  }
  #pragma unroll
  for (int r=0;r<4;++r){
    #pragma unroll
    for (int g=0; g<4; ++g){
      int row = r*16 + kg*4 + g;           // C/D: row=(lane>>4)*4+reg
      float gt = r_gt[row];
      float s = 0.f;
      #pragma unroll
      for (int c=0;c<4;++c){
        float x = acc[r][c][g] + stv[c] + gt*wbv[c];
        s += gelu_fast(x)*w2v[c];
      }
      s += __shfl_xor(s,1); s += __shfl_xor(s,2);
      s += __shfl_xor(s,4); s += __shfl_xor(s,8);
      if (l15 == 0) pdred[w][row] = s;
    }
  }
  __syncthreads();
  if (tid < 64){
    float v = rb2[0];
    #pragma unroll
    for (int ww = 0; ww < 8; ++ww) v += pdred[ww][tid];
    float residual = 0.35f*tanhf(v) * r_resmul[tid];
    float gt = r_gt[tid];
    out[m0+tid] = clampf(gt + residual, -1.2f, 1.2f)*r_speech[tid]
                + clampf(gt, -r_tau[tid], r_tau[tid])*r_silc[tid];
  }
}

// ---------------------------------------------------------------------------
extern "C" void kernel_launch(void* const* d_in, const int* in_sizes, int n_in,
                              void* d_out, int out_size, void* d_ws, size_t ws_size,
                              hipStream_t stream)
{
  const int*   content_units  = (const int*)  d_in[0];
  const float* log_anchor     = (const float*)d_in[1];
  const float* unit_mask      = (const float*)d_in[2];
  const float* sealed_mask    = (const float*)d_in[3];
  const float* sep_hint       = (const float*)d_in[4];
  const float* edge_cue       = (const float*)d_in[5];
  const float* global_rate    = (const float*)d_in[6];
  const float* local_rate_ema = (const float*)d_in[7];
  const float* silence_mask   = (const float*)d_in[8];
  const float* spk_embed      = (const float*)d_in[9];
  const float* embed          = (const float*)d_in[10];
  const float* feat_W         = (const float*)d_in[11];
  const float* feat_b         = (const float*)d_in[12];
  const float* spk_W          = (const float*)d_in[13];
  const float* spk_b          = (const float*)d_in[14];
  const float* cW1            = (const float*)d_in[15];
  const float* cb1            = (const float*)d_in[16];
  const float* cW2            = (const float*)d_in[17];
  const float* cb2            = (const float*)d_in[18];
  const float* rW1            = (const float*)d_in[19];
  const float* rb1            = (const float*)d_in[20];
  const float* rW2            = (const float*)d_in[21];
  const float* rb2            = (const float*)d_in[22];
  float* out = (float*)d_out;

  float* ws       = (float*)d_ws;
  float* lr_seq   = ws;                  // 32768
  float* prefix   = ws + 32768;          // 32768
  float* spk_ctx  = ws + 65536;          // 8192
  float* spk_pb   = ws + 73728;          // 8192
  float* cpart    = ws + 81920;          // 128
  unsigned short* BtG = (unsigned short*)(ws + 82048);   // 512 KB bf16

  k_p1<<<160, 512, 0, stream>>>(log_anchor, unit_mask, sealed_mask, silence_mask,
                                local_rate_ema, spk_embed, spk_W, spk_b, rW1,
                                lr_seq, prefix, spk_ctx, BtG);
  k_p2<<<256, 512, 0, stream>>>(spk_ctx, global_rate, cW1, cb1, cW2, rW1, rb1,
                                spk_pb, cpart);
  k_heavy<<<M_/64, 512, 0, stream>>>(content_units, log_anchor, unit_mask, sealed_mask,
                                     sep_hint, edge_cue, global_rate, silence_mask,
                                     embed, feat_W, feat_b, rW1, rW2, rb2, cb2,
                                     lr_seq, prefix, spk_pb, cpart, BtG, out);
}